// Round 1
// baseline (8178.548 us; speedup 1.0000x reference)
//
#include <hip/hip_runtime.h>
#include <hip/hip_bf16.h>
#include <stdint.h>

#define BATCH 4096
#define UNITS 1024
#define NSTEP 128

typedef __attribute__((ext_vector_type(4))) float f32x4;
typedef __attribute__((ext_vector_type(8))) short s16x8;

__device__ __forceinline__ void gload16(const void* g, void* l) {
  __builtin_amdgcn_global_load_lds(
      (const __attribute__((address_space(1))) unsigned int*)g,
      (__attribute__((address_space(3))) unsigned int*)l, 16, 0, 0);
}

__device__ __forceinline__ float fsigmoid(float x) {
  return 1.0f / (1.0f + __expf(-x));
}
__device__ __forceinline__ float ftanh(float x) {
  return 1.0f - 2.0f / (__expf(2.0f * x) + 1.0f);
}

// Transpose recurrent_kernel [1024][4096] f32 -> Rt0[4096][1024] bf16 (plain)
// and Rt1[4096][1024] bf16 (folded: R + dense_w (x) kernel).
__global__ void prep_weights(const float* __restrict__ R,
                             const float* __restrict__ ker,   // [4096]
                             const float* __restrict__ dw,    // [1024]
                             __hip_bfloat16* __restrict__ Rt0,
                             __hip_bfloat16* __restrict__ Rt1) {
  __shared__ float tile[32][33];
  __shared__ float dws[32];
  const int n0 = blockIdx.x * 32;   // column of R (gate*1024+unit), row of Rt
  const int k0 = blockIdx.y * 32;   // row of R (input unit), col of Rt
  const int tx = threadIdx.x;       // 0..31
  const int ty = threadIdx.y;       // 0..7
#pragma unroll
  for (int i = 0; i < 4; ++i) {
    int k = ty + i * 8;
    tile[k][tx] = R[(size_t)(k0 + k) * 4096 + n0 + tx];  // coalesced in n
  }
  if (ty == 0) dws[tx] = dw[k0 + tx];
  __syncthreads();
#pragma unroll
  for (int i = 0; i < 4; ++i) {
    int n = ty + i * 8;              // local n
    float v = tile[tx][n];           // = R[k0+tx][n0+n]
    int gn = n0 + n, gk = k0 + tx;
    size_t o = (size_t)gn * 1024 + gk;          // coalesced in k
    Rt0[o] = __float2bfloat16(v);
    Rt1[o] = __float2bfloat16(v + dws[tx] * ker[gn]);
  }
}

// Initialize h0 (bf16), c0 (f32), bias1 = bias + dense_b*kernel, out = dense_b.
__global__ void prep_state(const float* __restrict__ feat,   // [4096][512]
                           const float* __restrict__ bias,   // [4096]
                           const float* __restrict__ ker,    // [4096]
                           const float* __restrict__ db,     // [1]
                           float* __restrict__ bias1,
                           __hip_bfloat16* __restrict__ hA,
                           float* __restrict__ c,
                           float* __restrict__ out) {
  const int total = BATCH * UNITS;
  const float dbv = db[0];
  for (int i = blockIdx.x * blockDim.x + threadIdx.x; i < total;
       i += gridDim.x * blockDim.x) {
    int b = i >> 10, u = i & 1023;
    float v = feat[b * 512 + (u & 511)];   // concat([features,features])
    hA[i] = __float2bfloat16(v);
    c[i] = v;
    if (i < 4096) bias1[i] = bias[i] + dbv * ker[i];
    if (i < BATCH * NSTEP) out[i] = dbv;
  }
}

// One LSTM step: z = h @ Rt^T + bias (fused gates), update c, emit h_next bf16,
// atomically accumulate pred = h_new @ dense_w into out[:, t].
// Block: 256 threads (4 waves). Tile: 64 rows (batch) x 64 units x 4 gates.
// Wave w: rows 0..63, units [w*16, w*16+16), all 4 gates.
__global__ __launch_bounds__(256) void lstm_step(
    const __hip_bfloat16* __restrict__ hin,   // [4096][1024]
    const __hip_bfloat16* __restrict__ Bm,    // Rt [4096][1024] (n = g*1024+u)
    const float* __restrict__ biasv,          // [4096]
    float* __restrict__ c,                    // [4096][1024] f32 (in/out)
    __hip_bfloat16* __restrict__ hout,        // [4096][1024]
    const float* __restrict__ dw,             // dense_w [1024]
    float* __restrict__ out, int t) {
  // LDS: A tile [64 rows][64 k] bf16 = 8KB at 0; B tile [256 rows][64 k] = 32KB at 8192.
  __shared__ alignas(16) char lds[40960];
  const int tid = threadIdx.x;
  const int lane = tid & 63;
  const int w = tid >> 6;
  const int b0 = blockIdx.x * 64;
  const int u0 = blockIdx.y * 64;
  const int l15 = lane & 15;
  const int lhi = lane >> 4;

  const int ucol = u0 + w * 16 + l15;   // this lane's unit column

  f32x4 acc[4][4];   // [row-frag][gate]
#pragma unroll
  for (int g = 0; g < 4; ++g) {
    float bg = biasv[g * 1024 + ucol];
#pragma unroll
    for (int r = 0; r < 4; ++r) acc[r][g] = (f32x4){bg, bg, bg, bg};
  }

  const char* hbase = (const char*)(hin + (size_t)b0 * 1024);
  const char* bbase = (const char*)Bm;

  for (int ks = 0; ks < 16; ++ks) {
    const int k0 = ks * 64;
    __syncthreads();   // previous tile's compute done before overwrite
    // ---- stage A: 512 chunks of 16B. chunk = i*256 + w*64 + lane.
#pragma unroll
    for (int i = 0; i < 2; ++i) {
      int chunk = i * 256 + w * 64 + lane;
      int r = chunk >> 3;                         // local row
      int L = chunk * 16;                         // linear LDS byte
      int kbyte = (L ^ ((r & 7) << 4)) & 127;     // inverse-swizzled source
      gload16(hbase + ((size_t)r * 1024 + k0) * 2 + kbyte,
              lds + (i * 256 + w * 64) * 16);     // wave-uniform dest
    }
    // ---- stage B: 2048 chunks. row s = g*64+u -> global n = g*1024+u0+u.
#pragma unroll
    for (int i = 0; i < 8; ++i) {
      int chunk = i * 256 + w * 64 + lane;
      int s = chunk >> 3;
      int L = chunk * 16;
      int kbyte = (L ^ ((s & 7) << 4)) & 127;
      int n = (s >> 6) * 1024 + u0 + (s & 63);
      gload16(bbase + ((size_t)n * 1024 + k0) * 2 + kbyte,
              lds + 8192 + (i * 256 + w * 64) * 16);
    }
    __syncthreads();   // compiler emits vmcnt(0) drain here
    // ---- compute: BK=64 -> two K=32 MFMA groups
#pragma unroll
    for (int kk = 0; kk < 2; ++kk) {
      const int kb = (kk * 32 + lhi * 8) * 2;     // byte offset of 8 bf16
      s16x8 af[4], bf[4];
#pragma unroll
      for (int r = 0; r < 4; ++r) {
        int row = r * 16 + l15;
        int off = (row * 128 + kb) ^ ((row & 7) << 4);
        af[r] = *(const s16x8*)(lds + off);
      }
#pragma unroll
      for (int g = 0; g < 4; ++g) {
        int s = g * 64 + w * 16 + l15;
        int off = (s * 128 + kb) ^ ((s & 7) << 4);
        bf[g] = *(const s16x8*)(lds + 8192 + off);
      }
#pragma unroll
      for (int r = 0; r < 4; ++r)
#pragma unroll
        for (int g = 0; g < 4; ++g)
          acc[r][g] = __builtin_amdgcn_mfma_f32_16x16x32_bf16(af[r], bf[g],
                                                              acc[r][g], 0, 0, 0);
    }
  }

  // ---- epilogue: gates, c/h update, fused pred partial-dot
  const float dwv = dw[ucol];
#pragma unroll
  for (int r = 0; r < 4; ++r) {
#pragma unroll
    for (int j = 0; j < 4; ++j) {
      int b = b0 + r * 16 + lhi * 4 + j;
      size_t ci = (size_t)b * 1024 + ucol;
      float zi = acc[r][0][j], zf = acc[r][1][j];
      float zg = acc[r][2][j], zo = acc[r][3][j];
      float ig = fsigmoid(zi), fg = fsigmoid(zf);
      float gg = ftanh(zg), og = fsigmoid(zo);
      float cn = fg * c[ci] + ig * gg;
      c[ci] = cn;
      float hn = og * ftanh(cn);
      hout[ci] = __float2bfloat16(hn);
      // pred partial: sum over this wave's 16 units (lane bits 0..3)
      float p = hn * dwv;
      p += __shfl_xor(p, 1);
      p += __shfl_xor(p, 2);
      p += __shfl_xor(p, 4);
      p += __shfl_xor(p, 8);
      if (l15 == 0) atomicAdd(&out[(size_t)b * NSTEP + t], p);
    }
  }
}

extern "C" void kernel_launch(void* const* d_in, const int* in_sizes, int n_in,
                              void* d_out, int out_size, void* d_ws, size_t ws_size,
                              hipStream_t stream) {
  const float* feat = (const float*)d_in[0];  // [4096][512]
  const float* ker  = (const float*)d_in[1];  // [1][4096]
  const float* R    = (const float*)d_in[2];  // [1024][4096]
  const float* bias = (const float*)d_in[3];  // [4096]
  const float* dw   = (const float*)d_in[4];  // [1024][1]
  const float* db   = (const float*)d_in[5];  // [1]
  float* out = (float*)d_out;

  char* ws = (char*)d_ws;
  const size_t MB = 1024 * 1024;
  __hip_bfloat16* Rt0 = (__hip_bfloat16*)(ws);            // 8 MB
  __hip_bfloat16* Rt1 = (__hip_bfloat16*)(ws + 8 * MB);   // 8 MB
  float* bias1 = (float*)(ws + 16 * MB);                  // 16 KB
  __hip_bfloat16* hA = (__hip_bfloat16*)(ws + 16 * MB + 65536);  // 8 MB
  __hip_bfloat16* hB = (__hip_bfloat16*)(ws + 24 * MB + 65536);  // 8 MB
  float* cbuf = (float*)(ws + 32 * MB + 65536);           // 16 MB

  prep_weights<<<dim3(128, 32), dim3(32, 8), 0, stream>>>(R, ker, dw, Rt0, Rt1);
  prep_state<<<4096, 256, 0, stream>>>(feat, bias, ker, db, bias1, hA, cbuf, out);

  for (int t = 0; t < NSTEP; ++t) {
    const __hip_bfloat16* hin = (t & 1) ? hB : hA;
    __hip_bfloat16* hout = (t & 1) ? hA : hB;
    lstm_step<<<dim3(64, 16), 256, 0, stream>>>(
        hin, (t == 0) ? Rt0 : Rt1, (t == 0) ? bias : bias1, cbuf, hout, dw, out, t);
  }
}

// Round 2
// 6437.090 us; speedup vs baseline: 1.2705x; 1.2705x over previous
//
#include <hip/hip_runtime.h>
#include <hip/hip_bf16.h>
#include <stdint.h>

#define BATCH 4096
#define UNITS 1024
#define NSTEP 128

typedef __attribute__((ext_vector_type(4))) float f32x4;
typedef __attribute__((ext_vector_type(8))) short s16x8;

__device__ __forceinline__ void gload16(const void* g, void* l) {
  __builtin_amdgcn_global_load_lds(
      (const __attribute__((address_space(1))) unsigned int*)g,
      (__attribute__((address_space(3))) unsigned int*)l, 16, 0, 0);
}

__device__ __forceinline__ void block_barrier() {
  asm volatile("" ::: "memory");
  __builtin_amdgcn_s_barrier();
  asm volatile("" ::: "memory");
}

__device__ __forceinline__ float fsigmoid(float x) {
  return 1.0f / (1.0f + __expf(-x));
}
__device__ __forceinline__ float ftanh(float x) {
  return 1.0f - 2.0f / (__expf(2.0f * x) + 1.0f);
}

// Transpose recurrent_kernel [1024][4096] f32 -> permuted bf16 [4096][1024].
// Permutation: orig n = g*1024 + u, u = q*64 + wc*16 + ul
//   -> n' = q*256 + wc*64 + g*16 + ul
// so a block's 256 B-rows are contiguous and each wave's 64 columns are
// 16 units x 4 gates (gates lane-local in the epilogue).
// Rt0 = plain R; Rt1 = R + dense_w (x) kernel (autoregressive fold).
__global__ void prep_weights(const float* __restrict__ R,
                             const float* __restrict__ ker,   // [4096]
                             const float* __restrict__ dw,    // [1024]
                             __hip_bfloat16* __restrict__ Rt0,
                             __hip_bfloat16* __restrict__ Rt1) {
  __shared__ float tile[32][33];
  __shared__ float dws[32];
  const int n0 = blockIdx.x * 32;   // column of R (gate*1024+unit)
  const int k0 = blockIdx.y * 32;   // row of R (input unit)
  const int tx = threadIdx.x;       // 0..31
  const int ty = threadIdx.y;       // 0..7
#pragma unroll
  for (int i = 0; i < 4; ++i) {
    int k = ty + i * 8;
    tile[k][tx] = R[(size_t)(k0 + k) * 4096 + n0 + tx];  // coalesced in n
  }
  if (ty == 0) dws[tx] = dw[k0 + tx];
  __syncthreads();
#pragma unroll
  for (int i = 0; i < 4; ++i) {
    int n = ty + i * 8;
    float v = tile[tx][n];           // = R[k0+tx][n0+n]
    int gn = n0 + n, gk = k0 + tx;
    int g = gn >> 10, u = gn & 1023;
    int q = u >> 6, wc = (u >> 4) & 3, ul = u & 15;
    int np = q * 256 + wc * 64 + g * 16 + ul;
    size_t o = (size_t)np * 1024 + gk;          // coalesced in k
    Rt0[o] = __float2bfloat16(v);
    Rt1[o] = __float2bfloat16(v + dws[tx] * ker[gn]);
  }
}

// Initialize h0 (bf16), c0 (f32), bias1 = bias + dense_b*kernel, out = dense_b.
__global__ void prep_state(const float* __restrict__ feat,   // [4096][512]
                           const float* __restrict__ bias,   // [4096]
                           const float* __restrict__ ker,    // [4096]
                           const float* __restrict__ db,     // [1]
                           float* __restrict__ bias1,
                           __hip_bfloat16* __restrict__ hA,
                           float* __restrict__ c,
                           float* __restrict__ out) {
  const int total = BATCH * UNITS;
  const float dbv = db[0];
  for (int i = blockIdx.x * blockDim.x + threadIdx.x; i < total;
       i += gridDim.x * blockDim.x) {
    int b = i >> 10, u = i & 1023;
    float v = feat[b * 512 + (u & 511)];   // concat([features,features])
    hA[i] = __float2bfloat16(v);
    c[i] = v;
    if (i < 4096) bias1[i] = bias[i] + dbv * ker[i];
    if (i < BATCH * NSTEP) out[i] = dbv;
  }
}

// One LSTM step, 256x256 tile, BK=64, 8 waves (2M x 4N), counted-vmcnt pipeline.
// Wave (wr,wc): rows [wr*128, +128), cols = units [by*64+wc*16, +16) x 4 gates.
// LDS 128 KB: A dbuf 2x32KB @0, B dbuf 2x32KB @65536. Row stride 128 B with
// XOR-((r&7)<<4) swizzle (verified 0 bank conflicts in R1).
__global__ __launch_bounds__(512, 2) void lstm_step(
    const __hip_bfloat16* __restrict__ hin,   // [4096][1024]
    const __hip_bfloat16* __restrict__ Bp,    // permuted Rt [4096][1024]
    const float* __restrict__ biasv,          // [4096] (orig g*1024+u layout)
    float* __restrict__ c,                    // [4096][1024] f32
    __hip_bfloat16* __restrict__ hout,        // [4096][1024]
    const float* __restrict__ dw,             // [1024]
    float* __restrict__ out, int t) {
  extern __shared__ char lds[];   // 131072 bytes
  const int tid = threadIdx.x;
  const int lane = tid & 63;
  const int w = tid >> 6;
  const int l15 = lane & 15;
  const int lhi = lane >> 4;
  const int wr = w >> 2;          // 0..1
  const int wc = w & 3;           // 0..3

  // XCD-aware 4x8 rectangle: each XCD's 32 blocks share 4 A-panels + 8 B-panels.
  const int bi = blockIdx.x;
  const int xcd = bi & 7, slot = bi >> 3;
  const int bx = (xcd & 3) * 4 + (slot & 3);   // 0..15 (batch tiles)
  const int by = (xcd >> 2) * 8 + (slot >> 2); // 0..15 (unit tiles)

  const int ucol = by * 64 + wc * 16 + l15;
  const float dwv = dw[ucol];                  // issued before staging (oldest vmem)

  f32x4 acc[8][4];
#pragma unroll
  for (int g = 0; g < 4; ++g) {
    float bg = biasv[g * 1024 + ucol];
#pragma unroll
    for (int m = 0; m < 8; ++m) acc[m][g] = (f32x4){bg, bg, bg, bg};
  }

  const char* Asrc = (const char*)(hin + (size_t)bx * 256 * 1024);
  const char* Bsrc = (const char*)(Bp + (size_t)by * 256 * 1024);
  // staging: per-lane inverse-swizzled k-byte within a 128B row
  const int kb = ((lane & 7) * 16) ^ ((lane >> 3) << 4);
  // read-side swizzle (row&7 == l15&7 for both A and B fragments)
  const int swz = (l15 & 7) << 4;

  auto STAGE = [&](int kt) {   // 8 gload16/thread: A 4 + B 4
    const int k0b = kt * 128;  // byte offset of K-tile within row
    char* Ad = lds + (kt & 1) * 32768;
    char* Bd = lds + 65536 + (kt & 1) * 32768;
#pragma unroll
    for (int j = 0; j < 4; ++j) {
      int r = (w * 4 + j) * 8 + (lane >> 3);   // local row 0..255
      gload16(Asrc + (size_t)r * 2048 + k0b + kb, Ad + (w * 4 + j) * 1024);
      gload16(Bsrc + (size_t)r * 2048 + k0b + kb, Bd + (w * 4 + j) * 1024);
    }
  };

  STAGE(0);
  STAGE(1);
  asm volatile("s_waitcnt vmcnt(8)" ::: "memory");  // tile 0 landed
  block_barrier();

  for (int kt = 0; kt < 16; ++kt) {
    const char* Ab = lds + (kt & 1) * 32768;
    const char* Bb = lds + 65536 + (kt & 1) * 32768;
    // ---- phase A (kk=0): read frags, MFMA
    s16x8 a0[8], b0[4];
#pragma unroll
    for (int m = 0; m < 8; ++m) {
      int row = wr * 128 + m * 16 + l15;
      a0[m] = *(const s16x8*)(Ab + row * 128 + ((lhi * 16) ^ swz));
    }
#pragma unroll
    for (int g = 0; g < 4; ++g) {
      int srow = wc * 64 + g * 16 + l15;
      b0[g] = *(const s16x8*)(Bb + srow * 128 + ((lhi * 16) ^ swz));
    }
    __builtin_amdgcn_s_setprio(1);
#pragma unroll
    for (int m = 0; m < 8; ++m)
#pragma unroll
      for (int g = 0; g < 4; ++g)
        acc[m][g] = __builtin_amdgcn_mfma_f32_16x16x32_bf16(a0[m], b0[g],
                                                            acc[m][g], 0, 0, 0);
    __builtin_amdgcn_s_setprio(0);
    // ---- phase B (kk=1): read frags
    s16x8 a1[8], b1[4];
#pragma unroll
    for (int m = 0; m < 8; ++m) {
      int row = wr * 128 + m * 16 + l15;
      a1[m] = *(const s16x8*)(Ab + row * 128 + ((64 + lhi * 16) ^ swz));
    }
#pragma unroll
    for (int g = 0; g < 4; ++g) {
      int srow = wc * 64 + g * 16 + l15;
      b1[g] = *(const s16x8*)(Bb + srow * 128 + ((64 + lhi * 16) ^ swz));
    }
    asm volatile("s_waitcnt lgkmcnt(0)" ::: "memory");  // all my reads done
    __builtin_amdgcn_sched_barrier(0);                   // rule #18
    block_barrier();                  // all waves done reading this buffer
    if (kt < 14) STAGE(kt + 2);       // overwrite just-consumed buffer
    __builtin_amdgcn_s_setprio(1);
#pragma unroll
    for (int m = 0; m < 8; ++m)
#pragma unroll
      for (int g = 0; g < 4; ++g)
        acc[m][g] = __builtin_amdgcn_mfma_f32_16x16x32_bf16(a1[m], b1[g],
                                                            acc[m][g], 0, 0, 0);
    __builtin_amdgcn_s_setprio(0);
    // counted wait: leave t+2's 8 loads in flight; drain t+1's
    if (kt < 14) asm volatile("s_waitcnt vmcnt(8)" ::: "memory");
    else         asm volatile("s_waitcnt vmcnt(0)" ::: "memory");
    block_barrier();
  }

  // ---- epilogue: gates, c/h update, fused pred partial-dot
#pragma unroll
  for (int m = 0; m < 8; ++m) {
#pragma unroll
    for (int j = 0; j < 4; ++j) {
      int b = bx * 256 + wr * 128 + m * 16 + lhi * 4 + j;
      size_t ci = (size_t)b * 1024 + ucol;
      float zi = acc[m][0][j], zf = acc[m][1][j];
      float zg = acc[m][2][j], zo = acc[m][3][j];
      float ig = fsigmoid(zi), fg = fsigmoid(zf);
      float gg = ftanh(zg), og = fsigmoid(zo);
      float cn = fg * c[ci] + ig * gg;
      c[ci] = cn;
      float hn = og * ftanh(cn);
      hout[ci] = __float2bfloat16(hn);
      float p = hn * dwv;
      p += __shfl_xor(p, 1);
      p += __shfl_xor(p, 2);
      p += __shfl_xor(p, 4);
      p += __shfl_xor(p, 8);
      if (l15 == 0) atomicAdd(&out[(size_t)b * NSTEP + t], p);
    }
  }
}

extern "C" void kernel_launch(void* const* d_in, const int* in_sizes, int n_in,
                              void* d_out, int out_size, void* d_ws, size_t ws_size,
                              hipStream_t stream) {
  const float* feat = (const float*)d_in[0];  // [4096][512]
  const float* ker  = (const float*)d_in[1];  // [1][4096]
  const float* R    = (const float*)d_in[2];  // [1024][4096]
  const float* bias = (const float*)d_in[3];  // [4096]
  const float* dw   = (const float*)d_in[4];  // [1024][1]
  const float* db   = (const float*)d_in[5];  // [1]
  float* out = (float*)d_out;

  char* ws = (char*)d_ws;
  const size_t MB = 1024 * 1024;
  __hip_bfloat16* Rt0 = (__hip_bfloat16*)(ws);            // 8 MB (permuted)
  __hip_bfloat16* Rt1 = (__hip_bfloat16*)(ws + 8 * MB);   // 8 MB (permuted+fold)
  float* bias1 = (float*)(ws + 16 * MB);                  // 16 KB
  __hip_bfloat16* hA = (__hip_bfloat16*)(ws + 16 * MB + 65536);  // 8 MB
  __hip_bfloat16* hB = (__hip_bfloat16*)(ws + 24 * MB + 65536);  // 8 MB
  float* cbuf = (float*)(ws + 32 * MB + 65536);           // 16 MB

  // 128 KB dynamic LDS needs the opt-in (idempotent, capture-safe: no enqueue)
  hipFuncSetAttribute((const void*)lstm_step,
                      hipFuncAttributeMaxDynamicSharedMemorySize, 131072);

  prep_weights<<<dim3(128, 32), dim3(32, 8), 0, stream>>>(R, ker, dw, Rt0, Rt1);
  prep_state<<<4096, 256, 0, stream>>>(feat, bias, ker, db, bias1, hA, cbuf, out);

  for (int t = 0; t < NSTEP; ++t) {
    const __hip_bfloat16* hin = (t & 1) ? hB : hA;
    __hip_bfloat16* hout = (t & 1) ? hA : hB;
    lstm_step<<<256, 512, 131072, stream>>>(
        hin, (t == 0) ? Rt0 : Rt1, (t == 0) ? bias : bias1, cbuf, hout, dw, out, t);
  }
}